// Round 1
// baseline (951.012 us; speedup 1.0000x reference)
//
#include <hip/hip_runtime.h>
#include <math.h>

#define BLOCK 1024
#define WPB 16       // waves per block
#define RCHUNK 8     // rows per wave-iteration

// ---------------------------------------------------------------------------
// SNN/actor path for RR rows starting at xp (= x + row0*256), one wave.
// lane = output feature j. Weights come from LDS in blocked layout:
//   Wb[(k>>2)*256 + j*4 + (k&3)] = W[j][k]   (conflict-free ds_read_b128)
// ---------------------------------------------------------------------------
template<int RR>
__device__ __forceinline__ void snn_rows(const float* __restrict__ xp,
                                         const float* __restrict__ W1b,
                                         const float* __restrict__ W2b,
                                         const float* __restrict__ Wob,
                                         float* __restrict__ outp,
                                         int lane, float b1r, float b2r, float bor,
                                         float betac, float thr, float betao)
{
    float acc[RR];
#pragma unroll
    for (int r = 0; r < RR; ++r) acc[r] = 0.f;

#pragma unroll 4
    for (int kb = 0; kb < 64; ++kb) {
        const float4 wv = *(const float4*)&W1b[kb * 256 + lane * 4];
#pragma unroll
        for (int r = 0; r < RR; ++r) {
            const float4 xv = *(const float4*)(xp + (size_t)r * 256 + kb * 4);
            acc[r] = fmaf(xv.x, wv.x, acc[r]);
            acc[r] = fmaf(xv.y, wv.y, acc[r]);
            acc[r] = fmaf(xv.z, wv.z, acc[r]);
            acc[r] = fmaf(xv.w, wv.w, acc[r]);
        }
    }

#pragma unroll
    for (int r = 0; r < RR; ++r) {
        const float c1 = acc[r] + b1r;
        // Only mem1 truly recurs across timesteps (carried mem2/mem3 are dead
        // in the reference step fn): 10 elementwise updates, then one pass of
        // the W2 / Wo matvecs at the final timestep.
        float m1 = 0.f;
#pragma unroll
        for (int t = 0; t < 10; ++t) {
            const float rst = ((m1 - thr) > 0.f) ? thr : 0.f;  // reset uses OLD mem
            m1 = fmaf(betac, m1, c1) - rst;
        }
        const bool s1 = (m1 - thr) > 0.f;                      // spk1 @ t=9
        const unsigned long long msk1 = __ballot(s1 ? 1 : 0);  // wave-uniform

        float c2 = b2r;
#pragma unroll
        for (int ib = 0; ib < 16; ++ib) {
            const float4 wv = *(const float4*)&W2b[ib * 256 + lane * 4];
            const unsigned m = (unsigned)(msk1 >> (4 * ib));
            c2 += __uint_as_float((0u - (m & 1u))        & __float_as_uint(wv.x));
            c2 += __uint_as_float((0u - ((m >> 1) & 1u)) & __float_as_uint(wv.y));
            c2 += __uint_as_float((0u - ((m >> 2) & 1u)) & __float_as_uint(wv.z));
            c2 += __uint_as_float((0u - ((m >> 3) & 1u)) & __float_as_uint(wv.w));
        }
        const float rst2 = s1 ? thr : 0.f;        // reset from NEW mem1 (ref bug kept)
        const float m2 = fmaf(betac, m1, c2) - rst2;
        const bool s2 = (m2 - thr) > 0.f;
        const unsigned long long msk2 = __ballot(s2 ? 1 : 0);

        float c3 = bor;
#pragma unroll
        for (int ib = 0; ib < 16; ++ib) {
            const float4 wv = *(const float4*)&Wob[ib * 256 + lane * 4];
            const unsigned m = (unsigned)(msk2 >> (4 * ib));
            c3 += __uint_as_float((0u - (m & 1u))        & __float_as_uint(wv.x));
            c3 += __uint_as_float((0u - ((m >> 1) & 1u)) & __float_as_uint(wv.y));
            c3 += __uint_as_float((0u - ((m >> 2) & 1u)) & __float_as_uint(wv.z));
            c3 += __uint_as_float((0u - ((m >> 3) & 1u)) & __float_as_uint(wv.w));
        }
        const float m3 = fmaf(betao, m2, c3);     // lif_none state = NEW mem2 (ref bug kept)
        outp[(size_t)r * 64 + lane] = tanhf(m3) * 3.14159265358979323846f;
    }
}

template<int RR>
__device__ __forceinline__ void critic_rows(const float* __restrict__ xp,
                                            const float* __restrict__ Wv1b,
                                            const float* __restrict__ Wv2b,
                                            float* __restrict__ hvb,   // per-wave LDS, 64*RCHUNK floats
                                            float* __restrict__ outp,
                                            int lane, float bv1r, float bv2r)
{
    float acc[RR];
#pragma unroll
    for (int r = 0; r < RR; ++r) acc[r] = 0.f;

#pragma unroll 4
    for (int kb = 0; kb < 64; ++kb) {
        const float4 wv = *(const float4*)&Wv1b[kb * 256 + lane * 4];
#pragma unroll
        for (int r = 0; r < RR; ++r) {
            const float4 xv = *(const float4*)(xp + (size_t)r * 256 + kb * 4);
            acc[r] = fmaf(xv.x, wv.x, acc[r]);
            acc[r] = fmaf(xv.y, wv.y, acc[r]);
            acc[r] = fmaf(xv.z, wv.z, acc[r]);
            acc[r] = fmaf(xv.w, wv.w, acc[r]);
        }
    }

    // h = relu(x@Wv1^T + bv1): lane-distributed; exchange through LDS so every
    // lane can read the full 64-vector for the second layer.
#pragma unroll
    for (int r = 0; r < RR; ++r) {
        const float hv = fmaxf(acc[r] + bv1r, 0.f);
        hvb[r * 64 + lane] = hv;
    }
    asm volatile("s_waitcnt lgkmcnt(0)" ::: "memory");  // within-wave write->read

#pragma unroll
    for (int r = 0; r < RR; ++r) {
        float cv = bv2r;
#pragma unroll
        for (int ib = 0; ib < 16; ++ib) {
            const float4 wv = *(const float4*)&Wv2b[ib * 256 + lane * 4];
            const float4 h4 = *(const float4*)&hvb[r * 64 + ib * 4];  // broadcast read
            cv = fmaf(wv.x, h4.x, cv);
            cv = fmaf(wv.y, h4.y, cv);
            cv = fmaf(wv.z, h4.z, cv);
            cv = fmaf(wv.w, h4.w, cv);
        }
        outp[(size_t)r * 64 + lane] = fmaxf(cv, 0.f);
    }
}

// ---------------------------------------------------------------------------
// Fused kernel: blocks [0, nblk_half) do the SNN/actor path, blocks
// [nblk_half, 2*nblk_half) do the critic path. 1 block/CU (LDS 112 KB),
// 16 waves = 4 waves/SIMD, waves run their row ranges independently.
// ---------------------------------------------------------------------------
__global__ __launch_bounds__(BLOCK, 4)
void snn_fused(const float* __restrict__ x,
               const float* __restrict__ W1,  const float* __restrict__ b1,
               const float* __restrict__ W2,  const float* __restrict__ b2,
               const float* __restrict__ Wo,  const float* __restrict__ bo,
               const float* __restrict__ beta_in, const float* __restrict__ thr_in,
               const float* __restrict__ beta_out,
               const float* __restrict__ Wv1, const float* __restrict__ bv1,
               const float* __restrict__ Wv2, const float* __restrict__ bv2,
               float* __restrict__ out, int B, int nblk_half, int rpw)
{
    extern __shared__ float lds[];
    float* Wbig = lds;             // 16384 floats: W1b or Wv1b
    float* Wsm0 = lds + 16384;     // 4096: W2b or Wv2b
    float* Wsm1 = lds + 20480;     // 4096: Wob (SNN) | hv buffers (critic)

    const int tid = threadIdx.x;
    const bool crit = ((int)blockIdx.x >= nblk_half);
    const int blk = crit ? ((int)blockIdx.x - nblk_half) : (int)blockIdx.x;

    // Stage weights into blocked LDS layout (one-time, ~negligible).
    if (!crit) {
        for (int idx = tid; idx < 64 * 256; idx += BLOCK) {
            const int j = idx >> 8, k = idx & 255;
            Wbig[(k >> 2) * 256 + (j << 2) + (k & 3)] = W1[idx];
        }
        for (int idx = tid; idx < 64 * 64; idx += BLOCK) {
            const int j = idx >> 6, i = idx & 63;
            const int p = (i >> 2) * 256 + (j << 2) + (i & 3);
            Wsm0[p] = W2[idx];
            Wsm1[p] = Wo[idx];
        }
    } else {
        for (int idx = tid; idx < 64 * 256; idx += BLOCK) {
            const int j = idx >> 8, k = idx & 255;
            Wbig[(k >> 2) * 256 + (j << 2) + (k & 3)] = Wv1[idx];
        }
        for (int idx = tid; idx < 64 * 64; idx += BLOCK) {
            const int j = idx >> 6, i = idx & 63;
            Wsm0[(i >> 2) * 256 + (j << 2) + (i & 3)] = Wv2[idx];
        }
    }
    __syncthreads();

    const int lane = tid & 63;
    const int w = __builtin_amdgcn_readfirstlane(tid >> 6);   // uniform wave id
    const long gw = (long)blk * WPB + w;
    const long row_begin = gw * (long)rpw;

    if (!crit) {
        const float b1r = b1[lane], b2r = b2[lane], bor = bo[lane];
        const float betac = fminf(fmaxf(beta_in[lane], 0.f), 1.f);
        const float thr = thr_in[lane];
        const float betao = fminf(fmaxf(beta_out[0], 0.f), 1.f);
        for (int c = 0; c < rpw; c += RCHUNK) {
            const long row0 = row_begin + c;
            if (row0 >= B) break;
            if (row0 + RCHUNK <= B) {
                snn_rows<RCHUNK>(x + (size_t)row0 * 256, Wbig, Wsm0, Wsm1,
                                 out + (size_t)row0 * 64,
                                 lane, b1r, b2r, bor, betac, thr, betao);
            } else {
                for (long rr = row0; rr < B; ++rr)
                    snn_rows<1>(x + (size_t)rr * 256, Wbig, Wsm0, Wsm1,
                                out + (size_t)rr * 64,
                                lane, b1r, b2r, bor, betac, thr, betao);
            }
        }
    } else {
        const float bv1r = bv1[lane], bv2r = bv2[lane];
        float* hvb = lds + 20480 + (tid >> 6) * (64 * RCHUNK);
        for (int c = 0; c < rpw; c += RCHUNK) {
            const long row0 = row_begin + c;
            if (row0 >= B) break;
            if (row0 + RCHUNK <= B) {
                critic_rows<RCHUNK>(x + (size_t)row0 * 256, Wbig, Wsm0, hvb,
                                    out + (size_t)B * 64 + (size_t)row0 * 64,
                                    lane, bv1r, bv2r);
            } else {
                for (long rr = row0; rr < B; ++rr)
                    critic_rows<1>(x + (size_t)rr * 256, Wbig, Wsm0, hvb,
                                   out + (size_t)B * 64 + (size_t)rr * 64,
                                   lane, bv1r, bv2r);
            }
        }
    }
}

extern "C" void kernel_launch(void* const* d_in, const int* in_sizes, int n_in,
                              void* d_out, int out_size, void* d_ws, size_t ws_size,
                              hipStream_t stream)
{
    const float* x        = (const float*)d_in[0];
    const float* W1       = (const float*)d_in[1];
    const float* b1       = (const float*)d_in[2];
    const float* W2       = (const float*)d_in[3];
    const float* b2       = (const float*)d_in[4];
    const float* Wo       = (const float*)d_in[5];
    const float* bo       = (const float*)d_in[6];
    const float* beta_in  = (const float*)d_in[7];
    const float* thr_in   = (const float*)d_in[8];
    const float* beta_out = (const float*)d_in[9];
    const float* Wv1      = (const float*)d_in[10];
    const float* bv1      = (const float*)d_in[11];
    const float* Wv2      = (const float*)d_in[12];
    const float* bv2      = (const float*)d_in[13];
    float* out = (float*)d_out;

    const int B = in_sizes[0] / 256;

    const int nblk_half = 256;                 // 256 SNN blocks + 256 critic blocks
    const int nwaves = nblk_half * WPB;        // 4096 waves per role
    int rpw = (B + nwaves - 1) / nwaves;
    rpw = ((rpw + RCHUNK - 1) / RCHUNK) * RCHUNK;   // 32 for B=131072

    const int lds_bytes = (16384 + 4096 + 16 * 64 * RCHUNK) * 4;  // 114688
    hipFuncSetAttribute((const void*)snn_fused,
                        hipFuncAttributeMaxDynamicSharedMemorySize, lds_bytes);

    hipLaunchKernelGGL(snn_fused, dim3(2 * nblk_half), dim3(BLOCK), lds_bytes, stream,
                       x, W1, b1, W2, b2, Wo, bo, beta_in, thr_in, beta_out,
                       Wv1, bv1, Wv2, bv2, out, B, nblk_half, rpw);
}